// Round 7
// baseline (332.635 us; speedup 1.0000x reference)
//
#include <hip/hip_runtime.h>
#include <math.h>

// Chained bilinear lookup: out = bilinear(grid0, bilinear(grid1, x)),
// sigmoid per corner sample (both stages).
//
// Shapes: x (N,2) f32; grid1 (U1,U1,2) f32, U1=2080; grid0 (U0,U0,3) f32,
// U0=520; out (N,3) f32.
//
// PRECISION CONTRACT (rounds 0-5, PASSING at absmax 3.9e-3 / thr 1.96e-2):
//  - Ref is a faithful per-op float32 numpy pipeline; stage-1 output is
//    multiplied by 520 in stage 2 (errors amplified ~520x).
//  - su = x*U must be a SINGLE f32 rounded mul (inline-asm v_mul_f32 —
//    fast-math otherwise contracts su-floor into fma => 0.04 absmax).
//  - Table sigmoids via f64 exp + f64 divide, rounded once to f32.
//  - f32 blends as written (R5-validated).
//
// PERF (R5 counters): query 179us, FETCH 600MB (2 x 64B lines/point, 16B
// used), VALUBusy 11% -> request/latency bound. This round: float4 row
// loads (stage-1: 2 loads/pt), float4-padded grid0 cells (stage-2: 4
// aligned dwordx4), 2 points/thread for MLP, nontemporal x/out streams.
// NOTE: __builtin_nontemporal_* requires NATIVE vector types (ext_vector),
// HIP float2/float4 classes are rejected (R6 compile fail).

typedef float f32x2 __attribute__((ext_vector_type(2)));
typedef float f32x4 __attribute__((ext_vector_type(4)));

__device__ __forceinline__ float mul_rn_nocontract(float a, float b) {
    float r;
    asm("v_mul_f32 %0, %1, %2" : "=v"(r) : "v"(a), "v"(b));
    return r;
}

__device__ __forceinline__ float sigmoid_f64(float t) {
    double e = exp(-(double)t);          // f64 exp: no fast-math shortcut
    return (float)(1.0 / (1.0 + e));     // f64 divide, round once to f32
}

__device__ __forceinline__ float sigmoid_fast(float t) {
    return 1.0f / (1.0f + __expf(-t));   // non-amplified use only
}

// ---- Phase A1: elementwise sigmoid of grid1 (float4-vectorized) ----
__global__ void __launch_bounds__(256) sigmoid_table_kernel(
    const float4* __restrict__ in, float4* __restrict__ out, int n4)
{
    int i = blockIdx.x * blockDim.x + threadIdx.x;
    if (i >= n4) return;
    float4 v = in[i];
    float4 r;
    r.x = sigmoid_f64(v.x);
    r.y = sigmoid_f64(v.y);
    r.z = sigmoid_f64(v.z);
    r.w = sigmoid_f64(v.w);
    out[i] = r;
}

// ---- Phase A2: sigmoid grid0 and pad 3->4 floats per cell ----
__global__ void __launch_bounds__(256) sigmoid_pad_kernel(
    const float* __restrict__ g0, float4* __restrict__ s0p, int ncells)
{
    int j = blockIdx.x * blockDim.x + threadIdx.x;
    if (j >= ncells) return;
    float a = g0[3 * j + 0];
    float b = g0[3 * j + 1];
    float c = g0[3 * j + 2];
    s0p[j] = make_float4(sigmoid_f64(a), sigmoid_f64(b), sigmoid_f64(c), 0.0f);
}

// ---- Phase B: query kernel, 2 points per thread, padded grid0 ----
__global__ void __launch_bounds__(256) query2_kernel(
    const float* __restrict__ x,
    const float* __restrict__ s1,    // sigmoid(grid1), (U1,U1,2)
    const float4* __restrict__ s0p,  // sigmoid(grid0) padded, (U0*U0) float4
    float* __restrict__ out,         // (N,3)
    int N, int U1, int U0)
{
    int t = blockIdx.x * blockDim.x + threadIdx.x;
    int i0 = t * 2;
    if (i0 >= N) return;
    bool two = (i0 + 1 < N);

    f32x4 xv = __builtin_nontemporal_load(reinterpret_cast<const f32x4*>(x) + t);
    if (!two) { xv.z = xv.x; xv.w = xv.y; }  // tail: duplicate point 0

    float ux[2] = {xv.x, xv.z};
    float uy[2] = {xv.y, xv.w};

    float fU1 = (float)U1;
    int cA[2], cB[2];
    bool vwrap[2];
    float fu[2], fv[2];
#pragma unroll
    for (int p = 0; p < 2; ++p) {
        float su = mul_rn_nocontract(ux[p], fU1);
        float sv = mul_rn_nocontract(uy[p], fU1);
        float u0f = floorf(su), v0f = floorf(sv);
        fu[p] = su - u0f;                 // exact
        fv[p] = sv - v0f;
        int u0 = (int)u0f % U1; if (u0 < 0) u0 += U1;
        int v0 = (int)v0f % U1; if (v0 < 0) v0 += U1;
        int u1 = u0 + 1; if (u1 >= U1) u1 = 0;
        vwrap[p] = (v0 == U1 - 1);
        cA[p] = u0 * U1 + v0;             // row u0, col v0
        cB[p] = u1 * U1 + v0;             // row u1, col v0
    }

    // issue all 4 row loads (float4 = columns v0, v0+1 of one row; the
    // v-wrap case over-reads into the following region — owned memory,
    // value replaced by fixup below). 8B-aligned dwordx4.
    float4 rA[2], rB[2];
#pragma unroll
    for (int p = 0; p < 2; ++p) {
        rA[p] = *reinterpret_cast<const float4*>(s1 + 2 * cA[p]);
        rB[p] = *reinterpret_cast<const float4*>(s1 + 2 * cB[p]);
    }

    float kx[2], ky[2];
    const float2* s1v = reinterpret_cast<const float2*>(s1);
#pragma unroll
    for (int p = 0; p < 2; ++p) {
        if (vwrap[p]) {                   // rare: v0 == U1-1 -> col v1 = 0
            float2 c01 = s1v[cA[p] - (U1 - 1)];   // (u0, 0)
            float2 c11 = s1v[cB[p] - (U1 - 1)];   // (u1, 0)
            rA[p].z = c01.x; rA[p].w = c01.y;
            rB[p].z = c11.x; rB[p].w = c11.y;
        }
        float omfu = 1.0f - fu[p], omfv = 1.0f - fv[p];
        // t00=rA.xy t01=rA.zw t10=rB.xy t11=rB.zw
        kx[p] = (rA[p].x * omfu + rB[p].x * fu[p]) * omfv
              + (rA[p].z * omfu + rB[p].z * fu[p]) * fv[p];
        ky[p] = (rA[p].y * omfu + rB[p].y * fu[p]) * omfv
              + (rA[p].w * omfu + rB[p].w * fu[p]) * fv[p];
    }

    // ---- stage 2 ----
    float fU0 = (float)U0;
    int b00[2], b10[2], b01[2], b11[2];
    float fu2[2], fv2[2];
#pragma unroll
    for (int p = 0; p < 2; ++p) {
        float su2 = mul_rn_nocontract(kx[p], fU0);
        float sv2 = mul_rn_nocontract(ky[p], fU0);
        float u0f2 = floorf(su2), v0f2 = floorf(sv2);
        fu2[p] = su2 - u0f2;
        fv2[p] = sv2 - v0f2;
        int p0 = (int)u0f2 % U0; if (p0 < 0) p0 += U0;
        int q0 = (int)v0f2 % U0; if (q0 < 0) q0 += U0;
        int p1 = p0 + 1; if (p1 >= U0) p1 = 0;
        int q1 = q0 + 1; if (q1 >= U0) q1 = 0;
        b00[p] = p0 * U0 + q0;
        b10[p] = p1 * U0 + q0;
        b01[p] = p0 * U0 + q1;
        b11[p] = p1 * U0 + q1;
    }

    float4 c00[2], c10[2], c01[2], c11[2];
#pragma unroll
    for (int p = 0; p < 2; ++p) {
        c00[p] = s0p[b00[p]];
        c10[p] = s0p[b10[p]];
        c01[p] = s0p[b01[p]];
        c11[p] = s0p[b11[p]];
    }

    float res[6];
#pragma unroll
    for (int p = 0; p < 2; ++p) {
        float omfu2 = 1.0f - fu2[p], omfv2 = 1.0f - fv2[p];
        res[3*p+0] = (c00[p].x * omfu2 + c10[p].x * fu2[p]) * omfv2
                   + (c01[p].x * omfu2 + c11[p].x * fu2[p]) * fv2[p];
        res[3*p+1] = (c00[p].y * omfu2 + c10[p].y * fu2[p]) * omfv2
                   + (c01[p].y * omfu2 + c11[p].y * fu2[p]) * fv2[p];
        res[3*p+2] = (c00[p].z * omfu2 + c10[p].z * fu2[p]) * omfv2
                   + (c01[p].z * omfu2 + c11[p].z * fu2[p]) * fv2[p];
    }

    float* op = out + (size_t)i0 * 3;   // 8B-aligned (i0 even)
    if (two) {
        f32x2 s0v = {res[0], res[1]};
        f32x2 s1v2 = {res[2], res[3]};
        f32x2 s2v = {res[4], res[5]};
        __builtin_nontemporal_store(s0v, reinterpret_cast<f32x2*>(op));
        __builtin_nontemporal_store(s1v2, reinterpret_cast<f32x2*>(op + 2));
        __builtin_nontemporal_store(s2v, reinterpret_cast<f32x2*>(op + 4));
    } else {
        op[0] = res[0]; op[1] = res[1]; op[2] = res[2];
    }
}

// ---- Middle variant: R5's known-good unpadded query kernel ----
__global__ void __launch_bounds__(256) query_kernel_unpadded(
    const float* __restrict__ x,
    const float* __restrict__ s1,
    const float* __restrict__ s0,
    float* __restrict__ out,
    int N, int U1, int U0)
{
    int i = blockIdx.x * blockDim.x + threadIdx.x;
    if (i >= N) return;
    float2 uv = reinterpret_cast<const float2*>(x)[i];
    float fU1 = (float)U1;
    float su = mul_rn_nocontract(uv.x, fU1);
    float sv = mul_rn_nocontract(uv.y, fU1);
    float u0f = floorf(su), v0f = floorf(sv);
    float fu = su - u0f, fv = sv - v0f;
    int u0 = (int)u0f % U1; if (u0 < 0) u0 += U1;
    int v0 = (int)v0f % U1; if (v0 < 0) v0 += U1;
    int u1 = u0 + 1; if (u1 >= U1) u1 = 0;
    int v1 = v0 + 1; if (v1 >= U1) v1 = 0;
    const float2* s1v = reinterpret_cast<const float2*>(s1);
    float2 t00 = s1v[u0 * U1 + v0];
    float2 t10 = s1v[u1 * U1 + v0];
    float2 t01 = s1v[u0 * U1 + v1];
    float2 t11 = s1v[u1 * U1 + v1];
    float omfu = 1.0f - fu, omfv = 1.0f - fv;
    float kx = (t00.x * omfu + t10.x * fu) * omfv + (t01.x * omfu + t11.x * fu) * fv;
    float ky = (t00.y * omfu + t10.y * fu) * omfv + (t01.y * omfu + t11.y * fu) * fv;
    float fU0 = (float)U0;
    float su2 = mul_rn_nocontract(kx, fU0);
    float sv2 = mul_rn_nocontract(ky, fU0);
    float u0f2 = floorf(su2), v0f2 = floorf(sv2);
    float fu2 = su2 - u0f2, fv2 = sv2 - v0f2;
    int p0 = (int)u0f2 % U0; if (p0 < 0) p0 += U0;
    int q0 = (int)v0f2 % U0; if (q0 < 0) q0 += U0;
    int p1 = p0 + 1; if (p1 >= U0) p1 = 0;
    int q1 = q0 + 1; if (q1 >= U0) q1 = 0;
    int b00 = (p0 * U0 + q0) * 3, b10 = (p1 * U0 + q0) * 3;
    int b01 = (p0 * U0 + q1) * 3, b11 = (p1 * U0 + q1) * 3;
    float omfu2 = 1.0f - fu2, omfv2 = 1.0f - fv2;
    float r0 = (s0[b00+0] * omfu2 + s0[b10+0] * fu2) * omfv2
             + (s0[b01+0] * omfu2 + s0[b11+0] * fu2) * fv2;
    float r1 = (s0[b00+1] * omfu2 + s0[b10+1] * fu2) * omfv2
             + (s0[b01+1] * omfu2 + s0[b11+1] * fu2) * fv2;
    float r2 = (s0[b00+2] * omfu2 + s0[b10+2] * fu2) * omfv2
             + (s0[b01+2] * omfu2 + s0[b11+2] * fu2) * fv2;
    out[3*i+0] = r0; out[3*i+1] = r1; out[3*i+2] = r2;
}

// ---- Full fallback: all sigmoids in-kernel (ws too small) ----
__global__ void __launch_bounds__(256) query_kernel_fallback(
    const float* __restrict__ x,
    const float* __restrict__ g1,
    const float* __restrict__ g0,
    float* __restrict__ out,
    int N, int U1, int U0)
{
    int i = blockIdx.x * blockDim.x + threadIdx.x;
    if (i >= N) return;
    float2 uv = reinterpret_cast<const float2*>(x)[i];
    float fU1 = (float)U1;
    float su = mul_rn_nocontract(uv.x, fU1);
    float sv = mul_rn_nocontract(uv.y, fU1);
    float u0f = floorf(su), v0f = floorf(sv);
    float fu = su - u0f, fv = sv - v0f;
    int u0 = (int)u0f % U1; if (u0 < 0) u0 += U1;
    int v0 = (int)v0f % U1; if (v0 < 0) v0 += U1;
    int u1 = u0 + 1; if (u1 >= U1) u1 = 0;
    int v1 = v0 + 1; if (v1 >= U1) v1 = 0;
    const float2* g1v = reinterpret_cast<const float2*>(g1);
    float2 t00 = g1v[u0 * U1 + v0];
    float2 t10 = g1v[u1 * U1 + v0];
    float2 t01 = g1v[u0 * U1 + v1];
    float2 t11 = g1v[u1 * U1 + v1];
    float a00x = sigmoid_f64(t00.x), a00y = sigmoid_f64(t00.y);
    float a10x = sigmoid_f64(t10.x), a10y = sigmoid_f64(t10.y);
    float a01x = sigmoid_f64(t01.x), a01y = sigmoid_f64(t01.y);
    float a11x = sigmoid_f64(t11.x), a11y = sigmoid_f64(t11.y);
    float omfu = 1.0f - fu, omfv = 1.0f - fv;
    float kx = (a00x * omfu + a10x * fu) * omfv + (a01x * omfu + a11x * fu) * fv;
    float ky = (a00y * omfu + a10y * fu) * omfv + (a01y * omfu + a11y * fu) * fv;
    float fU0 = (float)U0;
    float su2 = mul_rn_nocontract(kx, fU0);
    float sv2 = mul_rn_nocontract(ky, fU0);
    float u0f2 = floorf(su2), v0f2 = floorf(sv2);
    float fu2 = su2 - u0f2, fv2 = sv2 - v0f2;
    int p0 = (int)u0f2 % U0; if (p0 < 0) p0 += U0;
    int q0 = (int)v0f2 % U0; if (q0 < 0) q0 += U0;
    int p1 = p0 + 1; if (p1 >= U0) p1 = 0;
    int q1 = q0 + 1; if (q1 >= U0) q1 = 0;
    int b00 = (p0 * U0 + q0) * 3, b10 = (p1 * U0 + q0) * 3;
    int b01 = (p0 * U0 + q1) * 3, b11 = (p1 * U0 + q1) * 3;
    float omfu2 = 1.0f - fu2, omfv2 = 1.0f - fv2;
    float r0 = (sigmoid_fast(g0[b00+0]) * omfu2 + sigmoid_fast(g0[b10+0]) * fu2) * omfv2
             + (sigmoid_fast(g0[b01+0]) * omfu2 + sigmoid_fast(g0[b11+0]) * fu2) * fv2;
    float r1 = (sigmoid_fast(g0[b00+1]) * omfu2 + sigmoid_fast(g0[b10+1]) * fu2) * omfv2
             + (sigmoid_fast(g0[b01+1]) * omfu2 + sigmoid_fast(g0[b11+1]) * fu2) * fv2;
    float r2 = (sigmoid_fast(g0[b00+2]) * omfu2 + sigmoid_fast(g0[b10+2]) * fu2) * omfv2
             + (sigmoid_fast(g0[b01+2]) * omfu2 + sigmoid_fast(g0[b11+2]) * fu2) * fv2;
    out[3*i+0] = r0; out[3*i+1] = r1; out[3*i+2] = r2;
}

extern "C" void kernel_launch(void* const* d_in, const int* in_sizes, int n_in,
                              void* d_out, int out_size, void* d_ws, size_t ws_size,
                              hipStream_t stream) {
    const float* x  = (const float*)d_in[0];
    const float* g1 = (const float*)d_in[1];
    const float* g0 = (const float*)d_in[2];
    float* out = (float*)d_out;

    int N = in_sizes[0] / 2;
    long long n1 = in_sizes[1];          // U1*U1*2
    long long n0 = in_sizes[2];          // U0*U0*3
    int U1 = (int)(sqrt((double)(n1 / 2)) + 0.5);
    int U0 = (int)(sqrt((double)(n0 / 3)) + 0.5);
    int ncells0 = U0 * U0;

    int block = 256;
    size_t need_pad   = ((size_t)n1 + (size_t)ncells0 * 4) * sizeof(float);
    size_t need_plain = ((size_t)n1 + (size_t)n0) * sizeof(float);

    if (ws_size >= need_pad && (n1 % 4) == 0 && (N % 2) == 0) {
        float* s1 = (float*)d_ws;
        float4* s0p = (float4*)(s1 + n1);
        int n1_4 = (int)(n1 / 4);
        sigmoid_table_kernel<<<(n1_4 + block - 1) / block, block, 0, stream>>>(
            (const float4*)g1, (float4*)s1, n1_4);
        sigmoid_pad_kernel<<<(ncells0 + block - 1) / block, block, 0, stream>>>(
            g0, s0p, ncells0);
        int nthreads = (N + 1) / 2;
        query2_kernel<<<(nthreads + block - 1) / block, block, 0, stream>>>(
            x, s1, s0p, out, N, U1, U0);
    } else if (ws_size >= need_plain && (n1 % 4) == 0 && (n0 % 4) == 0) {
        float* s1 = (float*)d_ws;
        float* s0 = s1 + n1;
        int n1_4 = (int)(n1 / 4), n0_4 = (int)(n0 / 4);
        sigmoid_table_kernel<<<(n1_4 + block - 1) / block, block, 0, stream>>>(
            (const float4*)g1, (float4*)s1, n1_4);
        sigmoid_table_kernel<<<(n0_4 + block - 1) / block, block, 0, stream>>>(
            (const float4*)g0, (float4*)s0, n0_4);
        query_kernel_unpadded<<<(N + block - 1) / block, block, 0, stream>>>(
            x, s1, s0, out, N, U1, U0);
    } else {
        query_kernel_fallback<<<(N + block - 1) / block, block, 0, stream>>>(
            x, g1, g0, out, N, U1, U0);
    }
}

// Round 8
// 263.751 us; speedup vs baseline: 1.2612x; 1.2612x over previous
//
#include <hip/hip_runtime.h>
#include <math.h>

// Chained bilinear lookup: out = bilinear(grid0, bilinear(grid1, x)),
// sigmoid per corner sample (both stages).
//
// Shapes: x (N,2) f32; grid1 (U1,U1,2) f32, U1=2080; grid0 (U0,U0,3) f32,
// U0=520; out (N,3) f32.
//
// PRECISION CONTRACT (rounds 0-5, PASSING at absmax 3.9e-3 / thr 1.96e-2):
//  - Ref is a faithful per-op float32 numpy pipeline; stage-1 output is
//    multiplied by 520 in stage 2 (errors amplified ~520x).
//  - su = x*U must be a SINGLE f32 rounded mul (inline-asm v_mul_f32 —
//    fast-math otherwise contracts su-floor into fma => 0.04 absmax).
//  - Table sigmoids via f64 exp + f64 divide, rounded once to f32.
//  - f32 blends as written (R5-validated).
//
// PERF HISTORY:
//  R5: 2 lines/point stage-1, FETCH 600MB, query 179us. dur ∝ FETCH at
//      ~3.4 TB/s random-line rate => line-count bound.
//  R7: padded grid0 (4.3MB) overflowed 4MB/XCD L2, FETCH 752MB, 222us.
//  R8 (this): corner-packed stage-1 table: per cell (u,v) store the 4
//      sigmoided corners (32B, wrap baked in, 32B-aligned => always ONE
//      64B line per point). grid0 back to unpadded 3.2MB (L2-resident).

typedef float f32x2 __attribute__((ext_vector_type(2)));
typedef float f32x4 __attribute__((ext_vector_type(4)));

__device__ __forceinline__ float mul_rn_nocontract(float a, float b) {
    float r;
    asm("v_mul_f32 %0, %1, %2" : "=v"(r) : "v"(a), "v"(b));
    return r;
}

__device__ __forceinline__ float sigmoid_f64(float t) {
    double e = exp(-(double)t);          // f64 exp: no fast-math shortcut
    return (float)(1.0 / (1.0 + e));     // f64 divide, round once to f32
}

__device__ __forceinline__ float sigmoid_fast(float t) {
    return 1.0f / (1.0f + __expf(-t));   // non-amplified use only
}

// ---- Phase A1: elementwise sigmoid of a table (float4-vectorized) ----
__global__ void __launch_bounds__(256) sigmoid_table_kernel(
    const float4* __restrict__ in, float4* __restrict__ out, int n4)
{
    int i = blockIdx.x * blockDim.x + threadIdx.x;
    if (i >= n4) return;
    float4 v = in[i];
    float4 r;
    r.x = sigmoid_f64(v.x);
    r.y = sigmoid_f64(v.y);
    r.z = sigmoid_f64(v.z);
    r.w = sigmoid_f64(v.w);
    out[i] = r;
}

// ---- Phase A2: corner-pack grid1 with sigmoid + wrap baked in ----
// Cell c=(u,v) -> 8 floats: [s(t00).xy s(t01).xy | s(t10).xy s(t11).xy]
__global__ void __launch_bounds__(256) pack_corners_kernel(
    const float* __restrict__ g1, float* __restrict__ pk, int U1)
{
    int c = blockIdx.x * blockDim.x + threadIdx.x;
    int ncells = U1 * U1;
    if (c >= ncells) return;
    int u = c / U1;
    int v = c - u * U1;
    int u1 = (u + 1 == U1) ? 0 : u + 1;
    int v1 = (v + 1 == U1) ? 0 : v + 1;
    const float2* g = reinterpret_cast<const float2*>(g1);
    float2 a = g[u * U1 + v];     // t00
    float2 b = g[u * U1 + v1];    // t01
    float2 d = g[u1 * U1 + v];    // t10
    float2 e = g[u1 * U1 + v1];   // t11
    float4 lo = make_float4(sigmoid_f64(a.x), sigmoid_f64(a.y),
                            sigmoid_f64(b.x), sigmoid_f64(b.y));
    float4 hi = make_float4(sigmoid_f64(d.x), sigmoid_f64(d.y),
                            sigmoid_f64(e.x), sigmoid_f64(e.y));
    float4* o = reinterpret_cast<float4*>(pk + (size_t)c * 8);
    o[0] = lo;
    o[1] = hi;
}

// ---- Phase B: query over packed stage-1 table + unpadded stage-2 ----
__global__ void __launch_bounds__(256) query_packed_kernel(
    const float* __restrict__ x,
    const float* __restrict__ pk,   // packed corners, U1*U1*8 floats
    const float* __restrict__ s0,   // sigmoid(grid0), (U0,U0,3)
    float* __restrict__ out,        // (N,3)
    int N, int U1, int U0)
{
    int i = blockIdx.x * blockDim.x + threadIdx.x;
    if (i >= N) return;

    f32x2 uv = __builtin_nontemporal_load(
        reinterpret_cast<const f32x2*>(x) + i);

    // stage-1 coords: single rounded f32 mul (contract-proof)
    float fU1 = (float)U1;
    float su = mul_rn_nocontract(uv.x, fU1);
    float sv = mul_rn_nocontract(uv.y, fU1);
    float u0f = floorf(su), v0f = floorf(sv);
    float fu = su - u0f;              // exact
    float fv = sv - v0f;
    int u0 = (int)u0f % U1; if (u0 < 0) u0 += U1;
    int v0 = (int)v0f % U1; if (v0 < 0) v0 += U1;

    // ONE 64B line: 32B-aligned packed cell
    const float4* cell = reinterpret_cast<const float4*>(pk)
                       + (size_t)(u0 * U1 + v0) * 2;
    float4 lo = cell[0];   // t00.xy t01.xy
    float4 hi = cell[1];   // t10.xy t11.xy

    float omfu = 1.0f - fu, omfv = 1.0f - fv;
    float kx = (lo.x * omfu + hi.x * fu) * omfv
             + (lo.z * omfu + hi.z * fu) * fv;
    float ky = (lo.y * omfu + hi.y * fu) * omfv
             + (lo.w * omfu + hi.w * fu) * fv;

    // stage 2 (R5-validated form, L2-resident 3.2MB table)
    float fU0 = (float)U0;
    float su2 = mul_rn_nocontract(kx, fU0);
    float sv2 = mul_rn_nocontract(ky, fU0);
    float u0f2 = floorf(su2), v0f2 = floorf(sv2);
    float fu2 = su2 - u0f2, fv2 = sv2 - v0f2;
    int p0 = (int)u0f2 % U0; if (p0 < 0) p0 += U0;
    int q0 = (int)v0f2 % U0; if (q0 < 0) q0 += U0;
    int p1 = p0 + 1; if (p1 >= U0) p1 = 0;
    int q1 = q0 + 1; if (q1 >= U0) q1 = 0;
    int b00 = (p0 * U0 + q0) * 3, b10 = (p1 * U0 + q0) * 3;
    int b01 = (p0 * U0 + q1) * 3, b11 = (p1 * U0 + q1) * 3;
    float omfu2 = 1.0f - fu2, omfv2 = 1.0f - fv2;
    float r0 = (s0[b00+0] * omfu2 + s0[b10+0] * fu2) * omfv2
             + (s0[b01+0] * omfu2 + s0[b11+0] * fu2) * fv2;
    float r1 = (s0[b00+1] * omfu2 + s0[b10+1] * fu2) * omfv2
             + (s0[b01+1] * omfu2 + s0[b11+1] * fu2) * fv2;
    float r2 = (s0[b00+2] * omfu2 + s0[b10+2] * fu2) * omfv2
             + (s0[b01+2] * omfu2 + s0[b11+2] * fu2) * fv2;
    out[3*i+0] = r0; out[3*i+1] = r1; out[3*i+2] = r2;
}

// ---- Middle variant: R5's known-good unpadded query kernel ----
__global__ void __launch_bounds__(256) query_kernel_unpadded(
    const float* __restrict__ x,
    const float* __restrict__ s1,
    const float* __restrict__ s0,
    float* __restrict__ out,
    int N, int U1, int U0)
{
    int i = blockIdx.x * blockDim.x + threadIdx.x;
    if (i >= N) return;
    float2 uv = reinterpret_cast<const float2*>(x)[i];
    float fU1 = (float)U1;
    float su = mul_rn_nocontract(uv.x, fU1);
    float sv = mul_rn_nocontract(uv.y, fU1);
    float u0f = floorf(su), v0f = floorf(sv);
    float fu = su - u0f, fv = sv - v0f;
    int u0 = (int)u0f % U1; if (u0 < 0) u0 += U1;
    int v0 = (int)v0f % U1; if (v0 < 0) v0 += U1;
    int u1 = u0 + 1; if (u1 >= U1) u1 = 0;
    int v1 = v0 + 1; if (v1 >= U1) v1 = 0;
    const float2* s1v = reinterpret_cast<const float2*>(s1);
    float2 t00 = s1v[u0 * U1 + v0];
    float2 t10 = s1v[u1 * U1 + v0];
    float2 t01 = s1v[u0 * U1 + v1];
    float2 t11 = s1v[u1 * U1 + v1];
    float omfu = 1.0f - fu, omfv = 1.0f - fv;
    float kx = (t00.x * omfu + t10.x * fu) * omfv + (t01.x * omfu + t11.x * fu) * fv;
    float ky = (t00.y * omfu + t10.y * fu) * omfv + (t01.y * omfu + t11.y * fu) * fv;
    float fU0 = (float)U0;
    float su2 = mul_rn_nocontract(kx, fU0);
    float sv2 = mul_rn_nocontract(ky, fU0);
    float u0f2 = floorf(su2), v0f2 = floorf(sv2);
    float fu2 = su2 - u0f2, fv2 = sv2 - v0f2;
    int p0 = (int)u0f2 % U0; if (p0 < 0) p0 += U0;
    int q0 = (int)v0f2 % U0; if (q0 < 0) q0 += U0;
    int p1 = p0 + 1; if (p1 >= U0) p1 = 0;
    int q1 = q0 + 1; if (q1 >= U0) q1 = 0;
    int b00 = (p0 * U0 + q0) * 3, b10 = (p1 * U0 + q0) * 3;
    int b01 = (p0 * U0 + q1) * 3, b11 = (p1 * U0 + q1) * 3;
    float omfu2 = 1.0f - fu2, omfv2 = 1.0f - fv2;
    float r0 = (s0[b00+0] * omfu2 + s0[b10+0] * fu2) * omfv2
             + (s0[b01+0] * omfu2 + s0[b11+0] * fu2) * fv2;
    float r1 = (s0[b00+1] * omfu2 + s0[b10+1] * fu2) * omfv2
             + (s0[b01+1] * omfu2 + s0[b11+1] * fu2) * fv2;
    float r2 = (s0[b00+2] * omfu2 + s0[b10+2] * fu2) * omfv2
             + (s0[b01+2] * omfu2 + s0[b11+2] * fu2) * fv2;
    out[3*i+0] = r0; out[3*i+1] = r1; out[3*i+2] = r2;
}

// ---- Full fallback: all sigmoids in-kernel (ws too small) ----
__global__ void __launch_bounds__(256) query_kernel_fallback(
    const float* __restrict__ x,
    const float* __restrict__ g1,
    const float* __restrict__ g0,
    float* __restrict__ out,
    int N, int U1, int U0)
{
    int i = blockIdx.x * blockDim.x + threadIdx.x;
    if (i >= N) return;
    float2 uv = reinterpret_cast<const float2*>(x)[i];
    float fU1 = (float)U1;
    float su = mul_rn_nocontract(uv.x, fU1);
    float sv = mul_rn_nocontract(uv.y, fU1);
    float u0f = floorf(su), v0f = floorf(sv);
    float fu = su - u0f, fv = sv - v0f;
    int u0 = (int)u0f % U1; if (u0 < 0) u0 += U1;
    int v0 = (int)v0f % U1; if (v0 < 0) v0 += U1;
    int u1 = u0 + 1; if (u1 >= U1) u1 = 0;
    int v1 = v0 + 1; if (v1 >= U1) v1 = 0;
    const float2* g1v = reinterpret_cast<const float2*>(g1);
    float2 t00 = g1v[u0 * U1 + v0];
    float2 t10 = g1v[u1 * U1 + v0];
    float2 t01 = g1v[u0 * U1 + v1];
    float2 t11 = g1v[u1 * U1 + v1];
    float a00x = sigmoid_f64(t00.x), a00y = sigmoid_f64(t00.y);
    float a10x = sigmoid_f64(t10.x), a10y = sigmoid_f64(t10.y);
    float a01x = sigmoid_f64(t01.x), a01y = sigmoid_f64(t01.y);
    float a11x = sigmoid_f64(t11.x), a11y = sigmoid_f64(t11.y);
    float omfu = 1.0f - fu, omfv = 1.0f - fv;
    float kx = (a00x * omfu + a10x * fu) * omfv + (a01x * omfu + a11x * fu) * fv;
    float ky = (a00y * omfu + a10y * fu) * omfv + (a01y * omfu + a11y * fu) * fv;
    float fU0 = (float)U0;
    float su2 = mul_rn_nocontract(kx, fU0);
    float sv2 = mul_rn_nocontract(ky, fU0);
    float u0f2 = floorf(su2), v0f2 = floorf(sv2);
    float fu2 = su2 - u0f2, fv2 = sv2 - v0f2;
    int p0 = (int)u0f2 % U0; if (p0 < 0) p0 += U0;
    int q0 = (int)v0f2 % U0; if (q0 < 0) q0 += U0;
    int p1 = p0 + 1; if (p1 >= U0) p1 = 0;
    int q1 = q0 + 1; if (q1 >= U0) q1 = 0;
    int b00 = (p0 * U0 + q0) * 3, b10 = (p1 * U0 + q0) * 3;
    int b01 = (p0 * U0 + q1) * 3, b11 = (p1 * U0 + q1) * 3;
    float omfu2 = 1.0f - fu2, omfv2 = 1.0f - fv2;
    float r0 = (sigmoid_fast(g0[b00+0]) * omfu2 + sigmoid_fast(g0[b10+0]) * fu2) * omfv2
             + (sigmoid_fast(g0[b01+0]) * omfu2 + sigmoid_fast(g0[b11+0]) * fu2) * fv2;
    float r1 = (sigmoid_fast(g0[b00+1]) * omfu2 + sigmoid_fast(g0[b10+1]) * fu2) * omfv2
             + (sigmoid_fast(g0[b01+1]) * omfu2 + sigmoid_fast(g0[b11+1]) * fu2) * fv2;
    float r2 = (sigmoid_fast(g0[b00+2]) * omfu2 + sigmoid_fast(g0[b10+2]) * fu2) * omfv2
             + (sigmoid_fast(g0[b01+2]) * omfu2 + sigmoid_fast(g0[b11+2]) * fu2) * fv2;
    out[3*i+0] = r0; out[3*i+1] = r1; out[3*i+2] = r2;
}

extern "C" void kernel_launch(void* const* d_in, const int* in_sizes, int n_in,
                              void* d_out, int out_size, void* d_ws, size_t ws_size,
                              hipStream_t stream) {
    const float* x  = (const float*)d_in[0];
    const float* g1 = (const float*)d_in[1];
    const float* g0 = (const float*)d_in[2];
    float* out = (float*)d_out;

    int N = in_sizes[0] / 2;
    long long n1 = in_sizes[1];          // U1*U1*2
    long long n0 = in_sizes[2];          // U0*U0*3
    int U1 = (int)(sqrt((double)(n1 / 2)) + 0.5);
    int U0 = (int)(sqrt((double)(n0 / 3)) + 0.5);
    long long ncells1 = (long long)U1 * U1;

    int block = 256;
    size_t need_packed = ((size_t)ncells1 * 8 + (size_t)n0) * sizeof(float);
    size_t need_plain  = ((size_t)n1 + (size_t)n0) * sizeof(float);

    if (ws_size >= need_packed && (n0 % 4) == 0) {
        float* pk = (float*)d_ws;                     // 138.4 MB packed
        float* s0 = pk + ncells1 * 8;                 // 3.2 MB sigmoided g0
        int n0_4 = (int)(n0 / 4);
        pack_corners_kernel<<<(int)((ncells1 + block - 1) / block), block, 0, stream>>>(
            g1, pk, U1);
        sigmoid_table_kernel<<<(n0_4 + block - 1) / block, block, 0, stream>>>(
            (const float4*)g0, (float4*)s0, n0_4);
        query_packed_kernel<<<(N + block - 1) / block, block, 0, stream>>>(
            x, pk, s0, out, N, U1, U0);
    } else if (ws_size >= need_plain && (n1 % 4) == 0 && (n0 % 4) == 0) {
        float* s1 = (float*)d_ws;
        float* s0 = s1 + n1;
        int n1_4 = (int)(n1 / 4), n0_4 = (int)(n0 / 4);
        sigmoid_table_kernel<<<(n1_4 + block - 1) / block, block, 0, stream>>>(
            (const float4*)g1, (float4*)s1, n1_4);
        sigmoid_table_kernel<<<(n0_4 + block - 1) / block, block, 0, stream>>>(
            (const float4*)g0, (float4*)s0, n0_4);
        query_kernel_unpadded<<<(N + block - 1) / block, block, 0, stream>>>(
            x, s1, s0, out, N, U1, U0);
    } else {
        query_kernel_fallback<<<(N + block - 1) / block, block, 0, stream>>>(
            x, g1, g0, out, N, U1, U0);
    }
}